// Round 1
// baseline (528.204 us; speedup 1.0000x reference)
//
#include <hip/hip_runtime.h>

typedef _Float16 f16;
typedef f16 f16x8 __attribute__((ext_vector_type(8)));
typedef float f32x4 __attribute__((ext_vector_type(4)));

#define T_STEPS 512
#define INPUT   12
#define HID     20
#define G4      80   // 4*H
#define KDIM    32   // 12 + 20 == MFMA K exactly
#define BW      4    // batches per wave
#define WPB     4    // waves per block
#define BLOCK   (WPB * 64)

__device__ __forceinline__ void lds_fence() {
    asm volatile("s_waitcnt lgkmcnt(0)" ::: "memory");
}

__device__ __forceinline__ float fast_sigmoid(float x) {
    // sigmoid(x) = 1 / (1 + 2^(-x*log2e)); exp2 overflow -> inf -> rcp -> 0 (correct saturation)
    float e = __builtin_amdgcn_exp2f(-1.4426950408889634f * x);
    return __builtin_amdgcn_rcpf(1.0f + e);
}
__device__ __forceinline__ float fast_tanh(float x) {
    // tanh(x) = 1 - 2/(1 + 2^(2x*log2e)); saturates correctly at +-1
    float e = __builtin_amdgcn_exp2f(2.8853900817779268f * x);
    return 1.0f - 2.0f * __builtin_amdgcn_rcpf(1.0f + e);
}

__global__ __launch_bounds__(BLOCK) void lstm_kernel(
    const float* __restrict__ x,      // [8192,512,12]
    const float* __restrict__ w_ih,   // [80,12]
    const float* __restrict__ w_hh,   // [80,20]
    const float* __restrict__ b_ih,   // [80]
    const float* __restrict__ b_hh,   // [80]
    const float* __restrict__ w_out,  // [10,20]
    const float* __restrict__ b_out,  // [10]
    float* __restrict__ out)          // [8192,10]
{
    __shared__ __align__(16) f16   Wc[G4][KDIM];            // combined [w_ih | w_hh], 5 KB
    __shared__ __align__(16) f16   Abuf_s[WPB][16][KDIM];   // per-wave A = [x | h], 1 KB each
    __shared__ __align__(16) float gbuf_s[WPB][G4][BW];     // per-wave gate staging, 1.25 KB each

    const int tid = threadIdx.x;

    // Build combined weight matrix in fp16 (once per block)
    for (int i = tid; i < G4 * KDIM; i += BLOCK) {
        int g = i >> 5, k = i & 31;
        float v = (k < INPUT) ? w_ih[g * INPUT + k] : w_hh[g * HID + (k - INPUT)];
        Wc[g][k] = (f16)v;
    }
    __syncthreads();

    const int wid  = tid >> 6;
    const int lane = tid & 63;
    const int c    = lane & 15;   // MFMA col / A-row index
    const int q    = lane >> 4;   // quad

    f16   (*Abuf)[KDIM] = Abuf_s[wid];
    float (*gbuf)[BW]   = gbuf_s[wid];

    // B fragments: B[k][n], lane holds Wc[tile*16 + c][q*8 .. q*8+7]  (16B contiguous)
    f16x8 bfrag[5];
#pragma unroll
    for (int nt = 0; nt < 5; ++nt)
        bfrag[nt] = *(const f16x8*)&Wc[nt * 16 + c][q * 8];

    // Update-phase roles:
    //   pass1 (all 64 lanes): batch b1 = q, unit u1 = c (units 0..15)
    //   pass2 (lanes 0..15):  batch b2 = lane>>2, unit u2 = 16 + (lane&3)
    const int u1 = c,            b1 = q;
    const int u2 = 16 + (lane & 3), b2 = lane >> 2;
    float bias1[4], bias2[4];
#pragma unroll
    for (int g = 0; g < 4; ++g) {
        bias1[g] = b_ih[g * HID + u1] + b_hh[g * HID + u1];
        bias2[g] = b_ih[g * HID + u2] + b_hh[g * HID + u2];
    }

    // Zero the whole A buffer (pad rows 4..15 stay zero forever; h starts at 0)
    {
        f16x8 z = {};
        *(f16x8*)&(((f16*)Abuf)[lane * 8]) = z;
    }
    lds_fence();

    const int wave_global = blockIdx.x * WPB + wid;
    const int b0 = wave_global * BW;

    // x loader role: lanes 0..47, one float per lane per step
    const int  xb    = lane / 12;
    const int  xi    = lane % 12;
    const bool xload = lane < 48;
    const float* xptr = x + (size_t)(b0 + xb) * (T_STEPS * INPUT) + xi;

    // Stage x(0), prefetch x(1)
    if (xload) Abuf[xb][xi] = (f16)xptr[0];
    float xv = 0.f;
    if (xload) xv = xptr[INPUT];
    lds_fence();

    float c1 = 0.f, c2 = 0.f;

#pragma unroll 1
    for (int t = 0; t < T_STEPS; ++t) {
        // A fragment: lane holds A[m = c][k = q*8 + j], j=0..7
        f16x8 afrag = *(const f16x8*)&Abuf[c][q * 8];
        lds_fence();  // read complete before x-region overwrite

        // Stage x(t+1) (loaded last iter), prefetch x(t+2)
        if (xload) Abuf[xb][xi] = (f16)xv;
        int tn = t + 2; if (tn > T_STEPS - 1) tn = T_STEPS - 1;
        if (xload) xv = xptr[(size_t)tn * INPUT];

        // gates[16 x 80] = A . Wc^T   (rows 0..3 real)
        f32x4 acc[5];
#pragma unroll
        for (int nt = 0; nt < 5; ++nt) {
            f32x4 z = {};
            acc[nt] = __builtin_amdgcn_mfma_f32_16x16x32_f16(afrag, bfrag[nt], z, 0, 0, 0);
        }

        // C layout: col = lane&15, row = (lane>>4)*4 + reg. Rows 0..3 live in lanes 0..15.
        // gbuf[g][b]: lane c writes regs 0..3 contiguous -> ds_write_b128
        if (lane < 16) {
#pragma unroll
            for (int nt = 0; nt < 5; ++nt)
                *(f32x4*)&gbuf[nt * 16 + c][0] = acc[nt];
        }
        lds_fence();

        // pass 1: all lanes, (b1, u1)
        {
            float gi = gbuf[u1][b1]           + bias1[0];
            float gf = gbuf[HID + u1][b1]     + bias1[1];
            float gg = gbuf[2 * HID + u1][b1] + bias1[2];
            float go = gbuf[3 * HID + u1][b1] + bias1[3];
            float ig = fast_sigmoid(gi), fg = fast_sigmoid(gf);
            float gt = fast_tanh(gg),    og = fast_sigmoid(go);
            c1 = fg * c1 + ig * gt;
            float h = og * fast_tanh(c1);
            Abuf[b1][INPUT + u1] = (f16)h;
        }
        // pass 2: lanes 0..15, (b2, u2)
        if (lane < 16) {
            float gi = gbuf[u2][b2]           + bias2[0];
            float gf = gbuf[HID + u2][b2]     + bias2[1];
            float gg = gbuf[2 * HID + u2][b2] + bias2[2];
            float go = gbuf[3 * HID + u2][b2] + bias2[3];
            float ig = fast_sigmoid(gi), fg = fast_sigmoid(gf);
            float gt = fast_tanh(gg),    og = fast_sigmoid(go);
            c2 = fg * c2 + ig * gt;
            float h = og * fast_tanh(c2);
            Abuf[b2][INPUT + u2] = (f16)h;
        }
        lds_fence();  // h writes visible before next A read
    }

    // Output projection: out[b][o] = h . w_out[o] + b_out[o]; h read back (fp16) from Abuf
    if (lane < 40) {
        int ob = lane / 10, oo = lane % 10;
        float s = b_out[oo];
#pragma unroll
        for (int u = 0; u < HID; ++u)
            s += w_out[oo * HID + u] * (float)Abuf[ob][INPUT + u];
        out[(size_t)(b0 + ob) * 10 + oo] = s;
    }
}

extern "C" void kernel_launch(void* const* d_in, const int* in_sizes, int n_in,
                              void* d_out, int out_size, void* d_ws, size_t ws_size,
                              hipStream_t stream) {
    const float* x     = (const float*)d_in[0];
    const float* w_ih  = (const float*)d_in[1];
    const float* w_hh  = (const float*)d_in[2];
    const float* b_ih  = (const float*)d_in[3];
    const float* b_hh  = (const float*)d_in[4];
    const float* w_out = (const float*)d_in[5];
    const float* b_out = (const float*)d_in[6];
    float* out = (float*)d_out;

    const int total_waves = 8192 / BW;       // 2048
    const int blocks = total_waves / WPB;    // 512
    hipLaunchKernelGGL(lstm_kernel, dim3(blocks), dim3(BLOCK), 0, stream,
                       x, w_ih, w_hh, b_ih, b_hh, w_out, b_out, out);
}

// Round 2
// 468.623 us; speedup vs baseline: 1.1271x; 1.1271x over previous
//
#include <hip/hip_runtime.h>

typedef _Float16 f16;
typedef f16 f16x8 __attribute__((ext_vector_type(8)));
typedef float f32x4 __attribute__((ext_vector_type(4)));

#define T_STEPS 512
#define INPUT   12
#define HID     20
#define KDIM    32      // 12 + 20 == MFMA K exactly
#define BATCH   16      // batches per block (full MFMA M)
#define WPB     5       // 5 waves = 5 N-tiles of 16 gate columns (80 = 4*H)
#define BLOCK   (WPB * 64)

static __device__ __forceinline__ void wave_lds_fence() {
    asm volatile("s_waitcnt lgkmcnt(0)" ::: "memory");
}
// raw barrier: waits LDS ops only (NOT vmcnt -> x prefetch stays in flight)
static __device__ __forceinline__ void block_barrier() {
    asm volatile("s_waitcnt lgkmcnt(0)\n\ts_barrier" ::: "memory");
}

static __device__ __forceinline__ float fast_sigmoid(float x) {
    float e = __builtin_amdgcn_exp2f(-1.4426950408889634f * x);
    return __builtin_amdgcn_rcpf(1.0f + e);
}
static __device__ __forceinline__ float fast_tanh(float x) {
    float e = __builtin_amdgcn_exp2f(2.8853900817779268f * x);
    return 1.0f - 2.0f * __builtin_amdgcn_rcpf(1.0f + e);
}

__global__ __launch_bounds__(BLOCK) void lstm_kernel(
    const float* __restrict__ x,      // [8192,512,12]
    const float* __restrict__ w_ih,   // [80,12]
    const float* __restrict__ w_hh,   // [80,20]
    const float* __restrict__ b_ih,   // [80]
    const float* __restrict__ b_hh,   // [80]
    const float* __restrict__ w_out,  // [10,20]
    const float* __restrict__ b_out,  // [10]
    float* __restrict__ out)          // [8192,10]
{
    // Column-permuted combined weights: column n (n = 16*w + c, c = 4*uu + g)
    // holds gate g of unit u = 4*w + uu  ->  each wave's tile contains all 4
    // gates of its 4 units  ->  update phase is wave-local.
    __shared__ __align__(16) f16   Wc[80][KDIM];             // 5 KB
    __shared__ __align__(16) f16   Abuf[2][BATCH][KDIM];     // 2 KB, double-buffered [x|h]
    __shared__ __align__(16) float wgbuf[WPB][16][16];       // 5 KB, per-wave gate staging

    const int tid  = threadIdx.x;
    const int wid  = tid >> 6;
    const int lane = tid & 63;

    // ---- build permuted weight matrix (once) ----
    for (int i = tid; i < 80 * KDIM; i += BLOCK) {
        int n = i >> 5, k = i & 31;
        int w = n >> 4, c = n & 15;
        int u = 4 * w + (c >> 2);          // unit
        int g = c & 3;                     // gate (i,f,g,o)
        int row = g * HID + u;             // original row in [w_ih | w_hh]
        float v = (k < INPUT) ? w_ih[row * INPUT + k] : w_hh[row * HID + (k - INPUT)];
        Wc[n][k] = (f16)v;
    }

    // ---- per-lane roles ----
    const int arow = lane & 15;            // A-row (batch) for MFMA frags
    const int aq   = lane >> 4;            // quad
    // update assignment: lane <-> (b, u)
    const int j  = lane & 3;
    const int uu = (lane >> 2) & 3;
    const int b  = 4 * aq + j;             // batch 0..15
    const int u  = 4 * wid + uu;           // unit 0..19

    float bias0 = b_ih[0 * HID + u] + b_hh[0 * HID + u];
    float bias1 = b_ih[1 * HID + u] + b_hh[1 * HID + u];
    float bias2 = b_ih[2 * HID + u] + b_hh[2 * HID + u];
    float bias3 = b_ih[3 * HID + u] + b_hh[3 * HID + u];

    // zero h-region of buf 0 (each lane its (b,u)); buf1 fully written in iter 0
    Abuf[0][b][INPUT + u] = (f16)0.f;

    // ---- x loader role: waves 0..3, lanes 0..47 -> one float/step ----
    const bool xload = (wid < 4) && (lane < 48);
    const int  xb    = 4 * wid + lane / 12;     // local batch 0..15
    const int  xi    = lane % 12;
    const float* xptr = x + (size_t)(blockIdx.x * BATCH + xb) * (T_STEPS * INPUT) + xi;

    float xv = 0.f;
    if (xload) {
        Abuf[0][xb][xi] = (f16)xptr[0];         // stage x(0)
        xv = xptr[INPUT];                       // prefetch x(1)
    }
    __syncthreads();   // Wc + x(0) + h(-1) visible

    // ---- B fragment: lane holds Wc[16*wid + (lane&15)][aq*8 .. +7] ----
    f16x8 bfrag = *(const f16x8*)&Wc[16 * wid + arow][aq * 8];

    float cc = 0.f;
    int p = 0;

#pragma unroll 1
    for (int t = 0; t < T_STEPS; ++t) {
        // A fragment from current buffer
        f16x8 afrag = *(const f16x8*)&Abuf[p][arow][aq * 8];

        // stage x(t+1) into next buffer, prefetch x(t+2)
        if (xload) Abuf[p ^ 1][xb][xi] = (f16)xv;
        int tn = t + 2; if (tn > T_STEPS - 1) tn = T_STEPS - 1;
        if (xload) xv = xptr[(size_t)tn * INPUT];

        // one MFMA: gates for this wave's 16 columns, 16 batches
        f32x4 z = {};
        f32x4 acc = __builtin_amdgcn_mfma_f32_16x16x32_f16(afrag, bfrag, z, 0, 0, 0);

        // C layout: col=lane&15, row=(lane>>4)*4+reg -> wgbuf[col][4*aq + reg]
        *(f32x4*)&wgbuf[wid][arow][4 * aq] = acc;
        wave_lds_fence();                       // wave-local: no barrier needed

        // gather this lane's 4 gates (columns 4*uu+g of own tile, batch b)
        float gi = wgbuf[wid][4 * uu + 0][b] + bias0;
        float gf = wgbuf[wid][4 * uu + 1][b] + bias1;
        float gg = wgbuf[wid][4 * uu + 2][b] + bias2;
        float go = wgbuf[wid][4 * uu + 3][b] + bias3;

        float ig = fast_sigmoid(gi), fg = fast_sigmoid(gf);
        float gt = fast_tanh(gg),    og = fast_sigmoid(go);
        cc = fg * cc + ig * gt;
        float h = og * fast_tanh(cc);

        Abuf[p ^ 1][b][INPUT + u] = (f16)h;     // publish h(t)
        block_barrier();                        // one barrier per step
        p ^= 1;
    }

    // ---- output projection: h(T-1) sits in Abuf[0] (512 steps -> p back to 0) ----
    if (tid < BATCH * 10) {
        int ob = tid / 10, oo = tid % 10;
        float s = b_out[oo];
#pragma unroll
        for (int u2 = 0; u2 < HID; ++u2)
            s += w_out[oo * HID + u2] * (float)Abuf[0][ob][INPUT + u2];
        out[(size_t)(blockIdx.x * BATCH + ob) * 10 + oo] = s;
    }
}

extern "C" void kernel_launch(void* const* d_in, const int* in_sizes, int n_in,
                              void* d_out, int out_size, void* d_ws, size_t ws_size,
                              hipStream_t stream) {
    const float* x     = (const float*)d_in[0];
    const float* w_ih  = (const float*)d_in[1];
    const float* w_hh  = (const float*)d_in[2];
    const float* b_ih  = (const float*)d_in[3];
    const float* b_hh  = (const float*)d_in[4];
    const float* w_out = (const float*)d_in[5];
    const float* b_out = (const float*)d_in[6];
    float* out = (float*)d_out;

    const int blocks = 8192 / BATCH;   // 512 blocks x 5 waves = 2560 waves (~2.5/SIMD)
    hipLaunchKernelGGL(lstm_kernel, dim3(blocks), dim3(BLOCK), 0, stream,
                       x, w_ih, w_hh, b_ih, b_hh, w_out, b_out, out);
}

// Round 3
// 428.165 us; speedup vs baseline: 1.2336x; 1.0945x over previous
//
#include <hip/hip_runtime.h>

typedef _Float16 f16;
typedef f16 f16x8 __attribute__((ext_vector_type(8)));
typedef float f32x4 __attribute__((ext_vector_type(4)));

#define T_STEPS 512
#define INPUT   12
#define HID     20
#define KDIM    32           // 12 + 20 == MFMA K exactly
#define BSTRIDE 40           // padded row stride (f16) -> conflict-free b128 reads
#define BATCH   16           // batches per block (MFMA N)
#define WPB     5            // 5 waves x 16 gate-rows = 80 = 4*H
#define BLOCK   (WPB * 64)

// raw barrier: drain LDS ops only (x prefetch stays in flight on vmcnt)
static __device__ __forceinline__ void block_barrier() {
    asm volatile("s_waitcnt lgkmcnt(0)\n\ts_barrier" ::: "memory");
}

static __device__ __forceinline__ float fast_sigmoid(float x) {
    float e = __builtin_amdgcn_exp2f(-1.4426950408889634f * x);
    return __builtin_amdgcn_rcpf(1.0f + e);
}
static __device__ __forceinline__ float fast_tanh(float x) {
    float e = __builtin_amdgcn_exp2f(2.8853900817779268f * x);
    return 1.0f - 2.0f * __builtin_amdgcn_rcpf(1.0f + e);
}

__global__ __launch_bounds__(BLOCK) void lstm_kernel(
    const float* __restrict__ x,      // [8192,512,12]
    const float* __restrict__ w_ih,   // [80,12]
    const float* __restrict__ w_hh,   // [80,20]
    const float* __restrict__ b_ih,   // [80]
    const float* __restrict__ b_hh,   // [80]
    const float* __restrict__ w_out,  // [10,20]
    const float* __restrict__ b_out,  // [10]
    float* __restrict__ out)          // [8192,10]
{
    // Row-permuted combined weights: tile row m (of wave w) = gate (m&3) of
    // unit 4w + (m>>2)  ->  MFMA D rows 4q..4q+3 = the 4 gates of unit 4w+q,
    // so each lane's 4 acc regs are its (batch, unit)'s gates. No regroup.
    __shared__ __align__(16) f16 Wc[80][KDIM];                 // 5 KB
    __shared__ __align__(16) f16 Bbuf[2][BATCH][BSTRIDE];      // 2.5 KB, [x|h] batch-major

    const int tid  = threadIdx.x;
    const int wid  = tid >> 6;
    const int lane = tid & 63;
    const int col  = lane & 15;        // MFMA N index = batch
    const int quad = lane >> 4;

    // ---- build permuted weight matrix (once) ----
    for (int i = tid; i < 80 * KDIM; i += BLOCK) {
        int n = i >> 5, k = i & 31;
        int g = n & 3;                       // gate (i,f,g,o)
        int u = 4 * (n >> 4) + ((n >> 2) & 3);
        int row = g * HID + u;               // original row of [w_ih | w_hh]
        float v = (k < INPUT) ? w_ih[row * INPUT + k] : w_hh[row * HID + (k - INPUT)];
        Wc[n][k] = (f16)v;
    }

    // ---- per-lane (batch, unit) ownership ----
    const int b = col;                 // batch 0..15
    const int u = 4 * wid + quad;      // unit 0..19

    // combined bias as MFMA C operand: reg r = bias of gate r, unit u
    f32x4 cbias;
#pragma unroll
    for (int g = 0; g < 4; ++g)
        cbias[g] = b_ih[g * HID + u] + b_hh[g * HID + u];

    // zero h region of buf 0
    Bbuf[0][b][INPUT + u] = (f16)0.f;

    // ---- x loader: tids 0..191 load one float/step (waves 0..2) ----
    const bool xload = tid < BATCH * INPUT;
    const int  xb    = tid / INPUT;
    const int  xi    = tid % INPUT;
    const float* xptr = x + (size_t)(blockIdx.x * BATCH + xb) * (T_STEPS * INPUT) + xi;

    float xv = 0.f;
    if (xload) {
        Bbuf[0][xb][xi] = (f16)xptr[0];      // stage x(0)
        xv = xptr[INPUT];                    // prefetch x(1)
    }
    __syncthreads();                         // Wc + x(0) + h(-1) visible

    // ---- constant A fragment: A[m=lane&15][k=quad*8+j] from own wave's tile ----
    const f16x8 afragW = *(const f16x8*)&Wc[16 * wid + col][quad * 8];

    float cc = 0.f;
    int p = 0;

#pragma unroll 1
    for (int t = 0; t < T_STEPS; ++t) {
        // B fragment: B[k=quad*8+j][n=col] = Bbuf[col][quad*8+j] (16B, conflict-free)
        f16x8 bfrag = *(const f16x8*)&Bbuf[p][col][quad * 8];

        // stage x(t+1) into next buffer, prefetch x(t+2)
        if (xload) Bbuf[p ^ 1][xb][xi] = (f16)xv;
        int tn = t + 2; if (tn > T_STEPS - 1) tn = T_STEPS - 1;
        if (xload) xv = xptr[(size_t)tn * INPUT];

        // gates (+bias via C operand): regs 0..3 = i,f,g,o of (b, u)
        f32x4 acc = __builtin_amdgcn_mfma_f32_16x16x32_f16(afragW, bfrag, cbias, 0, 0, 0);

        float ig = fast_sigmoid(acc[0]);
        float fg = fast_sigmoid(acc[1]);
        float gt = fast_tanh(acc[2]);
        float og = fast_sigmoid(acc[3]);
        cc = fg * cc + ig * gt;
        float h = og * fast_tanh(cc);

        Bbuf[p ^ 1][b][INPUT + u] = (f16)h;  // publish h(t)
        block_barrier();                     // one barrier per step
        p ^= 1;
    }

    // ---- output projection: T even -> h(T-1) sits in Bbuf[0] ----
    if (tid < BATCH * 10) {
        int ob = tid / 10, oo = tid % 10;
        float s = b_out[oo];
#pragma unroll
        for (int u2 = 0; u2 < HID; ++u2)
            s += w_out[oo * HID + u2] * (float)Bbuf[0][ob][INPUT + u2];
        out[(size_t)(blockIdx.x * BATCH + ob) * 10 + oo] = s;
    }
}

extern "C" void kernel_launch(void* const* d_in, const int* in_sizes, int n_in,
                              void* d_out, int out_size, void* d_ws, size_t ws_size,
                              hipStream_t stream) {
    const float* x     = (const float*)d_in[0];
    const float* w_ih  = (const float*)d_in[1];
    const float* w_hh  = (const float*)d_in[2];
    const float* b_ih  = (const float*)d_in[3];
    const float* b_hh  = (const float*)d_in[4];
    const float* w_out = (const float*)d_in[5];
    const float* b_out = (const float*)d_in[6];
    float* out = (float*)d_out;

    const int blocks = 8192 / BATCH;   // 512 blocks x 5 waves; ~2 blocks/CU
    hipLaunchKernelGGL(lstm_kernel, dim3(blocks), dim3(BLOCK), 0, stream,
                       x, w_ih, w_hh, b_ih, b_hh, w_out, b_out, out);
}

// Round 4
// 424.291 us; speedup vs baseline: 1.2449x; 1.0091x over previous
//
#include <hip/hip_runtime.h>

typedef _Float16 f16;
typedef f16 f16x8 __attribute__((ext_vector_type(8)));
typedef float f32x4 __attribute__((ext_vector_type(4)));

#define T_STEPS 512
#define INPUT   12
#define HID     20
#define KDIM    32           // 12 + 20 == MFMA K exactly
#define BSTRIDE 40           // padded row stride (f16) -> conflict-free b128 reads
#define BATCH   16           // batches per block (MFMA N)
#define WPB     5            // 5 waves x 16 gate-rows = 80 = 4*H
#define BLOCK   (WPB * 64)

// raw barrier: drain LDS ops only (x prefetch stays in flight on vmcnt)
static __device__ __forceinline__ void block_barrier() {
    asm volatile("s_waitcnt lgkmcnt(0)\n\ts_barrier" ::: "memory");
}

static __device__ __forceinline__ float fast_sigmoid(float x) {
    float e = __builtin_amdgcn_exp2f(-1.4426950408889634f * x);
    return __builtin_amdgcn_rcpf(1.0f + e);
}
static __device__ __forceinline__ float fast_tanh(float x) {
    float e = __builtin_amdgcn_exp2f(2.8853900817779268f * x);
    return 1.0f - 2.0f * __builtin_amdgcn_rcpf(1.0f + e);
}

__global__ __launch_bounds__(BLOCK) void lstm_kernel(
    const float* __restrict__ x,      // [8192,512,12]
    const float* __restrict__ w_ih,   // [80,12]
    const float* __restrict__ w_hh,   // [80,20]
    const float* __restrict__ b_ih,   // [80]
    const float* __restrict__ b_hh,   // [80]
    const float* __restrict__ w_out,  // [10,20]
    const float* __restrict__ b_out,  // [10]
    float* __restrict__ out)          // [8192,10]
{
    // Row-permuted combined weights: tile row m (of wave w) = gate (m&3) of
    // unit 4w + (m>>2)  ->  MFMA D rows 4q..4q+3 = the 4 gates of unit 4w+q,
    // so each lane's 4 acc regs are its (batch, unit)'s gates. No regroup.
    __shared__ __align__(16) f16 Wc[80][KDIM];                 // 5 KB
    __shared__ __align__(16) f16 Bbuf[2][BATCH][BSTRIDE];      // 2.5 KB, [x|h] batch-major

    const int tid  = threadIdx.x;
    const int wid  = tid >> 6;
    const int lane = tid & 63;
    const int col  = lane & 15;        // MFMA N index = batch
    const int quad = lane >> 4;

    // ---- build permuted weight matrix (once) ----
    for (int i = tid; i < 80 * KDIM; i += BLOCK) {
        int n = i >> 5, k = i & 31;
        int g = n & 3;                       // gate (i,f,g,o)
        int u = 4 * (n >> 4) + ((n >> 2) & 3);
        int row = g * HID + u;               // original row of [w_ih | w_hh]
        float v = (k < INPUT) ? w_ih[row * INPUT + k] : w_hh[row * HID + (k - INPUT)];
        Wc[n][k] = (f16)v;
    }

    // ---- per-lane (batch, unit) ownership ----
    const int b = col;                 // batch 0..15
    const int u = 4 * wid + quad;      // unit 0..19

    // combined bias as MFMA C operand: reg r = bias of gate r, unit u
    f32x4 cbias;
#pragma unroll
    for (int g = 0; g < 4; ++g)
        cbias[g] = b_ih[g * HID + u] + b_hh[g * HID + u];

    // zero h region of buf 0
    Bbuf[0][b][INPUT + u] = (f16)0.f;

    // ---- x loader: tids 0..191 (waves 0..2), one float/step each ----
    const bool xload = tid < BATCH * INPUT;
    const int  xb    = tid / INPUT;
    const int  xi    = tid % INPUT;
    const float* xptr = x + (size_t)(blockIdx.x * BATCH + xb) * (T_STEPS * INPUT) + xi;

    // 4-deep prefetch queue: q[j] holds x(t+1) for body j, reloaded 4 ahead.
    float q0 = 0.f, q1 = 0.f, q2 = 0.f, q3 = 0.f;
    if (xload) {
        Bbuf[0][xb][xi] = (f16)xptr[0];          // stage x(0)
        q0 = xptr[1 * INPUT];                    // x(1)
        q1 = xptr[2 * INPUT];                    // x(2)
        q2 = xptr[3 * INPUT];                    // x(3)
        q3 = xptr[4 * INPUT];                    // x(4)
    }
    __syncthreads();                             // Wc + x(0) + h(-1) visible

    // ---- constant A fragment: A[m=lane&15][k=quad*8+j] from own wave's tile ----
    const f16x8 afragW = *(const f16x8*)&Wc[16 * wid + col][quad * 8];

    float cc = 0.f;

    // one recurrence step; pj = buffer parity (compile-time after inlining)
    auto step = [&](int pj, float& qreg, int tload) {
        // B fragment: B[k=quad*8+j][n=col] = Bbuf[col][quad*8+j] (16B, conflict-free)
        f16x8 bfrag = *(const f16x8*)&Bbuf[pj][col][quad * 8];

        // stage x(t+1) into next buffer; reload queue slot with x(t+5)
        if (xload) Bbuf[pj ^ 1][xb][xi] = (f16)qreg;
        int tl = tload > T_STEPS - 1 ? T_STEPS - 1 : tload;
        if (xload) qreg = xptr[(size_t)tl * INPUT];

        // gates (+bias via C operand): regs 0..3 = i,f,g,o of (b, u)
        f32x4 acc = __builtin_amdgcn_mfma_f32_16x16x32_f16(afragW, bfrag, cbias, 0, 0, 0);

        float ig = fast_sigmoid(acc[0]);
        float fg = fast_sigmoid(acc[1]);
        float gt = fast_tanh(acc[2]);
        float og = fast_sigmoid(acc[3]);
        cc = fg * cc + ig * gt;
        float h = og * fast_tanh(cc);

        Bbuf[pj ^ 1][b][INPUT + u] = (f16)h;     // publish h(t)
        block_barrier();                         // one barrier per step
    };

#pragma unroll 1
    for (int t4 = 0; t4 < T_STEPS; t4 += 4) {
        step(0, q0, t4 + 5);
        step(1, q1, t4 + 6);
        step(0, q2, t4 + 7);
        step(1, q3, t4 + 8);
    }

    // ---- output projection: T even -> h(T-1) sits in Bbuf[0] ----
    if (tid < BATCH * 10) {
        int ob = tid / 10, oo = tid % 10;
        float s = b_out[oo];
#pragma unroll
        for (int u2 = 0; u2 < HID; ++u2)
            s += w_out[oo * HID + u2] * (float)Bbuf[0][ob][INPUT + u2];
        out[(size_t)(blockIdx.x * BATCH + ob) * 10 + oo] = s;
    }
}

extern "C" void kernel_launch(void* const* d_in, const int* in_sizes, int n_in,
                              void* d_out, int out_size, void* d_ws, size_t ws_size,
                              hipStream_t stream) {
    const float* x     = (const float*)d_in[0];
    const float* w_ih  = (const float*)d_in[1];
    const float* w_hh  = (const float*)d_in[2];
    const float* b_ih  = (const float*)d_in[3];
    const float* b_hh  = (const float*)d_in[4];
    const float* w_out = (const float*)d_in[5];
    const float* b_out = (const float*)d_in[6];
    float* out = (float*)d_out;

    const int blocks = 8192 / BATCH;   // 512 blocks x 5 waves; 2 blocks/CU
    hipLaunchKernelGGL(lstm_kernel, dim3(blocks), dim3(BLOCK), 0, stream,
                       x, w_ih, w_hh, b_ih, b_hh, w_out, b_out, out);
}